// Round 4
// baseline (324.468 us; speedup 1.0000x reference)
//
#include <hip/hip_runtime.h>
#include <hip/hip_bf16.h>
#include <cstdint>

#define B_ 8
#define S_ 2048
#define D_ 1024
#define U_ 1024
#define M_ (B_ * S_)   // 16384 rows

#define BM 128
#define BN 128
#define BK 64
#define NBLK 1024      // 128 m-blocks x 8 n-blocks; capacity-proof: <=1280 resident

typedef __bf16 bf16x8 __attribute__((ext_vector_type(8)));
typedef float  f32x4  __attribute__((ext_vector_type(4)));

__device__ __forceinline__ uint16_t f2bf(float f) {
  uint32_t u = __builtin_bit_cast(uint32_t, f);
  u += 0x7fffu + ((u >> 16) & 1u);   // RNE
  return (uint16_t)(u >> 16);
}

// async 16B global->LDS copy (lane-contiguous LDS destination)
__device__ __forceinline__ void async_copy16(const void* g, void* l) {
  typedef const __attribute__((address_space(1))) uint8_t* gp_t;
  typedef __attribute__((address_space(3))) uint8_t* lp_t;
  __builtin_amdgcn_global_load_lds((gp_t)(uintptr_t)g,
                                   (lp_t)(uint32_t)(uintptr_t)l, 16, 0, 0);
}

// Manual grid barrier, single-use. Safe: all NBLK blocks provably co-resident
// (LDS 32KB -> 5 blocks/CU limit, 1280 >= 1024). Agent-scope acq_rel for
// cross-XCD visibility (per-XCD L2s are not coherent).
__device__ __forceinline__ void grid_barrier(unsigned* ctr) {
  __syncthreads();
  if (threadIdx.x == 0) {
    __hip_atomic_fetch_add(ctr, 1u, __ATOMIC_ACQ_REL, __HIP_MEMORY_SCOPE_AGENT);
    while (__hip_atomic_load(ctr, __ATOMIC_ACQUIRE, __HIP_MEMORY_SCOPE_AGENT) <
           (unsigned)NBLK) {
      __builtin_amdgcn_s_sleep(8);
    }
  }
  __syncthreads();
}

// Single kernel: phase 1 = prep (w transpose, x->bf16, attn softmax),
// manual grid barrier, phase 2 = bf16 MFMA GEMM + fused activation epilogue.
__global__ __launch_bounds__(256, 4) void k_fused(
    const float* __restrict__ x, const float* __restrict__ w,
    const float* __restrict__ w_att, const float* __restrict__ b_att,
    const float* __restrict__ bias, const float* __restrict__ wf,
    const float* __restrict__ bfb,
    uint16_t* __restrict__ x_bf, uint16_t* __restrict__ wt,
    float* __restrict__ attn, unsigned* __restrict__ bar,
    float* __restrict__ out) {
  __shared__ uint16_t As[BM * BK];   // phase2 A tile; phase1 reuses as f32 transpose tile
  __shared__ uint16_t Bs[BN * BK];

  const int bid = blockIdx.x;
  const int t = threadIdx.x;
  const int wave = t >> 6, lane = t & 63;

  // ---------- phase 1a: w [D][U] -> wt [U][D] bf16, one 32x32 tile per block
  {
    float(*tile)[33] = reinterpret_cast<float(*)[33]>(As);   // 4224 B < 16 KB
    const int tx = t & 31, ty = t >> 5;
    const int c0 = (bid & 31) * 32;   // U
    const int r0 = (bid >> 5) * 32;   // D
#pragma unroll
    for (int i = 0; i < 4; i++) {
      int r = ty + i * 8;
      tile[r][tx] = w[(size_t)(r0 + r) * U_ + c0 + tx];
    }
    __syncthreads();
#pragma unroll
    for (int i = 0; i < 4; i++) {
      int r = ty + i * 8;
      wt[(size_t)(c0 + r) * D_ + r0 + tx] = f2bf(tile[tx][r]);
    }
  }

  // ---------- phase 1b: x -> bf16 + attn softmax, wave-per-row, 4 rows/wave
  {
    const float4* wa4 = reinterpret_cast<const float4*>(w_att);
#pragma unroll 1
    for (int rr = 0; rr < 4; rr++) {
      const int row = bid * 16 + wave * 4 + rr;
      const float4* xr = reinterpret_cast<const float4*>(x + (size_t)row * D_);
      float4 v[4];
#pragma unroll
      for (int i = 0; i < 4; i++) v[i] = xr[lane + 64 * i];   // coalesced 16 B/lane
      float4 p = {0.f, 0.f, 0.f, 0.f};
#pragma unroll
      for (int i = 0; i < 4; i++) {
        const int base = 4 * (lane + 64 * i);
        const float xe[4] = {v[i].x, v[i].y, v[i].z, v[i].w};
#pragma unroll
        for (int c = 0; c < 4; c++) {
          float4 wv = wa4[base + c];   // 16 KiB table, cache-hot
          p.x = fmaf(xe[c], wv.x, p.x);
          p.y = fmaf(xe[c], wv.y, p.y);
          p.z = fmaf(xe[c], wv.z, p.z);
          p.w = fmaf(xe[c], wv.w, p.w);
        }
        ushort4 hb;
        hb.x = f2bf(v[i].x); hb.y = f2bf(v[i].y);
        hb.z = f2bf(v[i].z); hb.w = f2bf(v[i].w);
        reinterpret_cast<ushort4*>(x_bf + (size_t)row * D_)[lane + 64 * i] = hb;
      }
#pragma unroll
      for (int off = 32; off > 0; off >>= 1) {
        p.x += __shfl_xor(p.x, off);
        p.y += __shfl_xor(p.y, off);
        p.z += __shfl_xor(p.z, off);
        p.w += __shfl_xor(p.w, off);
      }
      if (lane == 0) {
        float l0 = p.x + b_att[0], l1 = p.y + b_att[1];
        float l2 = p.z + b_att[2], l3 = p.w + b_att[3];
        float mx = fmaxf(fmaxf(l0, l1), fmaxf(l2, l3));
        float e0 = __expf(l0 - mx), e1 = __expf(l1 - mx);
        float e2 = __expf(l2 - mx), e3 = __expf(l3 - mx);
        float inv = __builtin_amdgcn_rcpf(e0 + e1 + e2 + e3);
        reinterpret_cast<float4*>(attn)[row] =
            make_float4(e0 * inv, e1 * inv, e2 * inv, e3 * inv);
      }
    }
  }

  // ---------- grid-wide barrier (device-scope => cross-XCD visibility)
  grid_barrier(bar);

  // ---------- phase 2: GEMM x_bf[M,D] @ wt[U,D]^T + fused epilogue
  const int l16 = lane & 15, quad = lane >> 4;
  const int wm = wave >> 1, wn = wave & 1;
  const int m0 = (bid >> 3) * BM;
  const int n0 = (bid & 7) * BN;

  const uint16_t* aBase = x_bf + (size_t)m0 * D_;
  const uint16_t* bBase = wt + (size_t)n0 * D_;

  f32x4 acc[4][4] = {};

  for (int k0 = 0; k0 < D_; k0 += BK) {
#pragma unroll
    for (int it = 0; it < 4; it++) {
      int c = t + it * 256;          // chunk id: per-wave lane-contiguous
      int r = c >> 3;                // tile row (m for A, n for B)
      int cs = c & 7;                // swizzled chunk slot
      int gc = cs ^ (r & 7);         // global chunk
      async_copy16(aBase + (size_t)r * D_ + k0 + gc * 8, (uint8_t*)As + c * 16);
      async_copy16(bBase + (size_t)r * D_ + k0 + gc * 8, (uint8_t*)Bs + c * 16);
    }
    __syncthreads();

#pragma unroll
    for (int ks = 0; ks < 2; ks++) {
      const int kcb = ks * 4;        // chunk base within row (kk/8)
      bf16x8 af[4], bfr[4];
#pragma unroll
      for (int i = 0; i < 4; i++) {
        int r = wm * 64 + i * 16 + l16;
        int cs = (kcb + quad) ^ (r & 7);
        af[i] = *reinterpret_cast<const bf16x8*>(&As[r * BK + cs * 8]);
      }
#pragma unroll
      for (int j = 0; j < 4; j++) {
        int n = wn * 64 + j * 16 + l16;
        int cs = (kcb + quad) ^ (n & 7);
        bfr[j] = *reinterpret_cast<const bf16x8*>(&Bs[n * BK + cs * 8]);
      }
#pragma unroll
      for (int i = 0; i < 4; i++)
#pragma unroll
        for (int j = 0; j < 4; j++)
          acc[i][j] = __builtin_amdgcn_mfma_f32_16x16x32_bf16(af[i], bfr[j], acc[i][j], 0, 0, 0);
    }
    __syncthreads();
  }

  // ---- fused epilogue: 4 activations (fast-math) + attention-weighted reduce
  float bu[4];
  float4 wf4[4], bf4[4];
#pragma unroll
  for (int j = 0; j < 4; j++) {
    int u = n0 + wn * 64 + j * 16 + l16;
    bu[j] = bias[u];
    wf4[j] = reinterpret_cast<const float4*>(wf)[u];
    bf4[j] = reinterpret_cast<const float4*>(bfb)[u];
  }
#pragma unroll
  for (int i = 0; i < 4; i++) {
#pragma unroll
    for (int r = 0; r < 4; r++) {
      int mg = m0 + wm * 64 + i * 16 + quad * 4 + r;   // C/D: row = quad*4+reg
      float4 at = reinterpret_cast<const float4*>(attn)[mg];
      float* orow = out + (size_t)mg * U_;
#pragma unroll
      for (int j = 0; j < 4; j++) {
        int u = n0 + wn * 64 + j * 16 + l16;            // C/D: col = lane&15
        float wsv = acc[i][j][r] + bu[j];
        float wa0 = fmaf(wsv, wf4[j].x, bf4[j].x);
        float wa1 = fmaf(wsv, wf4[j].y, bf4[j].y);
        float wa2 = fmaf(wsv, wf4[j].z, bf4[j].z);
        float wa3 = fmaf(wsv, wf4[j].w, bf4[j].w);
        float a_relu = fmaxf(wa0, 0.f);
        float a_sig = __builtin_amdgcn_rcpf(
            1.f + __builtin_amdgcn_exp2f(-1.4426950409f * wa1));
        float a_tanh = fmaf(2.f, __builtin_amdgcn_rcpf(
            1.f + __builtin_amdgcn_exp2f(-2.8853900818f * wa2)), -1.f);
        float y = wa3 * fmaf(0.044715f, wa3 * wa3, 1.f);
        float a_gelu = wa3 * __builtin_amdgcn_rcpf(
            1.f + __builtin_amdgcn_exp2f(-2.302207929f * y));
        orow[u] = at.x * a_relu + at.y * a_sig + at.z * a_tanh + at.w * a_gelu;
      }
    }
  }
}

extern "C" void kernel_launch(void* const* d_in, const int* in_sizes, int n_in,
                              void* d_out, int out_size, void* d_ws, size_t ws_size,
                              hipStream_t stream) {
  const float* x     = (const float*)d_in[0];
  const float* w     = (const float*)d_in[1];
  const float* b     = (const float*)d_in[2];
  const float* wf    = (const float*)d_in[3];
  const float* bfb   = (const float*)d_in[4];
  const float* w_att = (const float*)d_in[5];
  const float* b_att = (const float*)d_in[6];
  float* out = (float*)d_out;

  char* ws = (char*)d_ws;
  uint16_t* x_bf = (uint16_t*)ws;                          // 32 MiB
  uint16_t* w_t  = (uint16_t*)(ws + ((size_t)32 << 20));   // 2 MiB
  float*    attn = (float*)(ws + ((size_t)34 << 20));      // 256 KiB
  unsigned* bar  = (unsigned*)(ws + ((size_t)35 << 20));   // barrier counter

  hipMemsetAsync(bar, 0, 64, stream);   // d_ws is poisoned 0xAA each call
  k_fused<<<dim3(NBLK), 256, 0, stream>>>(x, w, w_att, b_att, b, wf, bfb,
                                          x_bf, w_t, attn, bar, out);
}

// Round 5
// 205.709 us; speedup vs baseline: 1.5773x; 1.5773x over previous
//
#include <hip/hip_runtime.h>
#include <hip/hip_bf16.h>
#include <cstdint>

#define B_ 8
#define S_ 2048
#define D_ 1024
#define U_ 1024
#define M_ (B_ * S_)   // 16384 rows

typedef __bf16 bf16x8 __attribute__((ext_vector_type(8)));
typedef float  f32x4  __attribute__((ext_vector_type(4)));

__device__ __forceinline__ uint16_t f2bf(float f) {
  uint32_t u = __builtin_bit_cast(uint32_t, f);
  u += 0x7fffu + ((u >> 16) & 1u);   // RNE
  return (uint16_t)(u >> 16);
}

// async 16B global->LDS copy (lane-contiguous LDS destination)
__device__ __forceinline__ void async_copy16(const void* g, void* l) {
  typedef const __attribute__((address_space(1))) uint8_t* gp_t;
  typedef __attribute__((address_space(3))) uint8_t* lp_t;
  __builtin_amdgcn_global_load_lds((gp_t)(uintptr_t)g,
                                   (lp_t)(uint32_t)(uintptr_t)l, 16, 0, 0);
}

// ---------------- kernel 1 (fused prep):
//   blocks [0, M_/4):      wave-per-row: x -> x_bf (bf16) + attn softmax (no barriers)
//   blocks [M_/4, +1024):  w [D][U] f32 -> wt [U][D] bf16 (LDS tile transpose)
__global__ __launch_bounds__(256) void k_prep(
    const float* __restrict__ x, const float* __restrict__ w_att,
    const float* __restrict__ b_att, const float* __restrict__ w,
    uint16_t* __restrict__ x_bf, float* __restrict__ attn,
    uint16_t* __restrict__ wt) {
  __shared__ float tile[32][33];     // used only by transpose blocks
  const int bid = blockIdx.x;
  if (bid < M_ / 4) {
    const int wave = threadIdx.x >> 6, lane = threadIdx.x & 63;
    const int row = bid * 4 + wave;
    const float4* xr = reinterpret_cast<const float4*>(x + (size_t)row * D_);
    const float4* wa4 = reinterpret_cast<const float4*>(w_att);
    float4 v[4];
#pragma unroll
    for (int i = 0; i < 4; i++) v[i] = xr[lane + 64 * i];   // 16 B/lane coalesced
    float4 p = {0.f, 0.f, 0.f, 0.f};
#pragma unroll
    for (int i = 0; i < 4; i++) {
      const int base = 4 * (lane + 64 * i);
      const float xe[4] = {v[i].x, v[i].y, v[i].z, v[i].w};
#pragma unroll
      for (int c = 0; c < 4; c++) {
        float4 wv = wa4[base + c];   // 16 KiB table, L1-hot
        p.x = fmaf(xe[c], wv.x, p.x);
        p.y = fmaf(xe[c], wv.y, p.y);
        p.z = fmaf(xe[c], wv.z, p.z);
        p.w = fmaf(xe[c], wv.w, p.w);
      }
      ushort4 hb;
      hb.x = f2bf(v[i].x); hb.y = f2bf(v[i].y);
      hb.z = f2bf(v[i].z); hb.w = f2bf(v[i].w);
      reinterpret_cast<ushort4*>(x_bf + (size_t)row * D_)[lane + 64 * i] = hb;
    }
    // in-wave butterfly reduce (no LDS, no barrier)
#pragma unroll
    for (int off = 32; off > 0; off >>= 1) {
      p.x += __shfl_xor(p.x, off);
      p.y += __shfl_xor(p.y, off);
      p.z += __shfl_xor(p.z, off);
      p.w += __shfl_xor(p.w, off);
    }
    if (lane == 0) {
      float l0 = p.x + b_att[0], l1 = p.y + b_att[1];
      float l2 = p.z + b_att[2], l3 = p.w + b_att[3];
      float mx = fmaxf(fmaxf(l0, l1), fmaxf(l2, l3));
      float e0 = __expf(l0 - mx), e1 = __expf(l1 - mx);
      float e2 = __expf(l2 - mx), e3 = __expf(l3 - mx);
      float inv = __builtin_amdgcn_rcpf(e0 + e1 + e2 + e3);
      reinterpret_cast<float4*>(attn)[row] =
          make_float4(e0 * inv, e1 * inv, e2 * inv, e3 * inv);
    }
  } else {
    const int wid = bid - M_ / 4;
    const int t = threadIdx.x;
    const int tx = t & 31, ty = t >> 5;
    const int c0 = (wid & 31) * 32;   // U
    const int r0 = (wid >> 5) * 32;   // D
#pragma unroll
    for (int i = 0; i < 4; i++) {
      int r = ty + i * 8;
      tile[r][tx] = w[(size_t)(r0 + r) * U_ + c0 + tx];
    }
    __syncthreads();
#pragma unroll
    for (int i = 0; i < 4; i++) {
      int r = ty + i * 8;
      wt[(size_t)(c0 + r) * D_ + r0 + tx] = f2bf(tile[tx][r]);
    }
  }
}

// ---------------- kernel 2: bf16 MFMA GEMM, A via LDS, B direct from L2-resident
// global (wt is 2 MB, fits per-XCD L2), + fused fast-math epilogue.
#define BM 128
#define BN 128
#define BK 64

__global__ __launch_bounds__(256, 4) void k_gemm_ep(
    const uint16_t* __restrict__ xbf, const uint16_t* __restrict__ wt,
    const float* __restrict__ bias, const float* __restrict__ wf,
    const float* __restrict__ bfb, const float* __restrict__ attn,
    float* __restrict__ out) {
  __shared__ uint16_t As[BM * BK];   // 16 KB: [row m][k], 8-elem chunks XOR-swizzled

  const int t = threadIdx.x;
  const int wave = t >> 6, lane = t & 63;
  const int l16 = lane & 15, quad = lane >> 4;
  const int wm = wave >> 1, wn = wave & 1;
  // XCD swizzle: same-m blocks share bid%8 -> same XCD -> A-tile L2 reuse (8x)
  const int bid = blockIdx.x;
  const int m0 = (bid & 127) * BM;
  const int n0 = (bid >> 7) * BN;

  const uint16_t* aBase = xbf + (size_t)m0 * D_;
  // per-lane B row base: row n = n0 + wn*64 + l16 (+ j*16), k-chunk at quad*8
  const uint16_t* bp = wt + (size_t)(n0 + wn * 64 + l16) * D_ + quad * 8;

  f32x4 acc[4][4] = {};

  for (int k0 = 0; k0 < D_; k0 += BK) {
#pragma unroll
    for (int it = 0; it < 4; it++) {
      int c = t + it * 256;          // A chunk id: per-wave lane-contiguous
      int r = c >> 3;                // tile row m
      int cs = c & 7;                // swizzled chunk slot
      int gc = cs ^ (r & 7);         // global chunk
      async_copy16(aBase + (size_t)r * D_ + k0 + gc * 8, (uint8_t*)As + c * 16);
    }
    __syncthreads();

#pragma unroll
    for (int ks = 0; ks < 2; ks++) {
      const int kcb = ks * 4;        // chunk base within row (kk/8)
      bf16x8 bfr[4];
#pragma unroll
      for (int j = 0; j < 4; j++)    // B direct from global (L2-hot): 16 B/lane
        bfr[j] = *reinterpret_cast<const bf16x8*>(
            bp + (size_t)j * 16 * D_ + k0 + ks * 32);
      bf16x8 af[4];
#pragma unroll
      for (int i = 0; i < 4; i++) {
        int r = wm * 64 + i * 16 + l16;
        int cs = (kcb + quad) ^ (r & 7);
        af[i] = *reinterpret_cast<const bf16x8*>(&As[r * BK + cs * 8]);
      }
#pragma unroll
      for (int i = 0; i < 4; i++)
#pragma unroll
        for (int j = 0; j < 4; j++)
          acc[i][j] = __builtin_amdgcn_mfma_f32_16x16x32_bf16(af[i], bfr[j], acc[i][j], 0, 0, 0);
    }
    __syncthreads();
  }

  // ---- fused epilogue: 4 activations (fast-math) + attention-weighted reduce
  float bu[4];
  float4 wf4[4], bf4[4];
#pragma unroll
  for (int j = 0; j < 4; j++) {
    int u = n0 + wn * 64 + j * 16 + l16;
    bu[j] = bias[u];
    wf4[j] = reinterpret_cast<const float4*>(wf)[u];
    bf4[j] = reinterpret_cast<const float4*>(bfb)[u];
  }
#pragma unroll
  for (int i = 0; i < 4; i++) {
#pragma unroll
    for (int r = 0; r < 4; r++) {
      int mg = m0 + wm * 64 + i * 16 + quad * 4 + r;   // C/D: row = quad*4+reg
      float4 at = reinterpret_cast<const float4*>(attn)[mg];
      float* orow = out + (size_t)mg * U_;
#pragma unroll
      for (int j = 0; j < 4; j++) {
        int u = n0 + wn * 64 + j * 16 + l16;            // C/D: col = lane&15
        float wsv = acc[i][j][r] + bu[j];
        float wa0 = fmaf(wsv, wf4[j].x, bf4[j].x);
        float wa1 = fmaf(wsv, wf4[j].y, bf4[j].y);
        float wa2 = fmaf(wsv, wf4[j].z, bf4[j].z);
        float wa3 = fmaf(wsv, wf4[j].w, bf4[j].w);
        float a_relu = fmaxf(wa0, 0.f);
        float a_sig = __builtin_amdgcn_rcpf(
            1.f + __builtin_amdgcn_exp2f(-1.4426950409f * wa1));
        float a_tanh = fmaf(2.f, __builtin_amdgcn_rcpf(
            1.f + __builtin_amdgcn_exp2f(-2.8853900818f * wa2)), -1.f);
        float y = wa3 * fmaf(0.044715f, wa3 * wa3, 1.f);
        float a_gelu = wa3 * __builtin_amdgcn_rcpf(
            1.f + __builtin_amdgcn_exp2f(-2.302207929f * y));
        orow[u] = at.x * a_relu + at.y * a_sig + at.z * a_tanh + at.w * a_gelu;
      }
    }
  }
}

extern "C" void kernel_launch(void* const* d_in, const int* in_sizes, int n_in,
                              void* d_out, int out_size, void* d_ws, size_t ws_size,
                              hipStream_t stream) {
  const float* x     = (const float*)d_in[0];
  const float* w     = (const float*)d_in[1];
  const float* b     = (const float*)d_in[2];
  const float* wf    = (const float*)d_in[3];
  const float* bfb   = (const float*)d_in[4];
  const float* w_att = (const float*)d_in[5];
  const float* b_att = (const float*)d_in[6];
  float* out = (float*)d_out;

  char* ws = (char*)d_ws;
  uint16_t* x_bf = (uint16_t*)ws;                          // 32 MiB
  uint16_t* w_t  = (uint16_t*)(ws + ((size_t)32 << 20));   // 2 MiB
  float*    attn = (float*)(ws + ((size_t)34 << 20));      // 256 KiB

  k_prep<<<dim3(M_ / 4 + 1024), 256, 0, stream>>>(x, w_att, b_att, w, x_bf, attn, w_t);
  k_gemm_ep<<<dim3(1024), 256, 0, stream>>>(x_bf, w_t, b, wf, bfb, attn, out);
}